// Round 3
// baseline (272.187 us; speedup 1.0000x reference)
//
#include <hip/hip_runtime.h>
#include <cstdint>
#include <climits>

// LeakyTopKActivation: out = x * mask * GAIN, mask = 1.0 on per-row top-k
// (k = 614 of 4096, stable ties by lowest index), LEAK=0.1 elsewhere.
//
// Two-kernel split:
//   A) select_kernel: wave-per-row, zero barriers, branch-free histogram
//      (dummy-bin trick: every element does exactly one LDS atomic; below-
//      bracket -> per-lane dummy bin 256+lane (2 lanes/bank = conflict-free),
//      >=HI clamps into bin 255). Suffix-scan -> exact bin -> gather pass
//      re-reads row (L1-hot) -> parallel rank -> exact (T, cut) -> d_ws.
//      Exact bit-binary-search fallback (global re-reads, cold) keeps
//      correctness independent of the data distribution.
//   B) apply_kernel: pure streaming out[i] = x[i] * (acc ? 3.0 : 0.3),
//      acc = x>T || (x==T && idx<cut). x is L3-resident after A.

namespace {
constexpr int   N_FEAT  = 4096;
constexpr int   KSEL    = 614;      // max(int(4096*0.15),1)
constexpr int   NB      = 256;      // real bins over [LO,HI); bin255 absorbs >=HI
constexpr int   NBD     = NB + 64;  // + per-lane dummy bins for f < LO
constexpr int   WPB     = 4;        // waves (rows) per block
constexpr int   THREADS = 64 * WPB;
constexpr float LO_BR   = 0.70f;
constexpr float HI_BR   = 1.40f;
constexpr float GAINF   = 3.0f;
constexpr float LEAKG   = 0.3f;     // LEAK * GAIN
constexpr int   M_LIST  = 32;       // max gathered candidates in chosen bin
}

__device__ __forceinline__ void wave_fence() {
    asm volatile("s_waitcnt lgkmcnt(0)" ::: "memory");
}

__device__ __forceinline__ uint32_t f2key(float f) {
    uint32_t u = __float_as_uint(f);
    return u ^ ((uint32_t)(((int32_t)u) >> 31) | 0x80000000u);
}
__device__ __forceinline__ float key2f(uint32_t k) {
    uint32_t u = (k & 0x80000000u) ? (k ^ 0x80000000u) : ~k;
    return __uint_as_float(u);
}

// ---------------------------------------------------------------- kernel A --
__global__ __launch_bounds__(THREADS, 6)
void select_kernel(const float* __restrict__ x, int2* __restrict__ tc,
                   int nrows) {
    const int lane = threadIdx.x & 63;
    const int wv   = threadIdx.x >> 6;
    const int row  = blockIdx.x * WPB + wv;   // wave-uniform
    if (row >= nrows) return;

    __shared__ unsigned int hist[WPB][NBD];
    __shared__ float        lv[WPB][M_LIST];
    __shared__ int          li[WPB][M_LIST];
    __shared__ unsigned int cnt[WPB];

    const float4* __restrict__ xv = (const float4*)(x + (size_t)row * N_FEAT);

    #pragma unroll
    for (int i = 0; i < NBD / 64; ++i) hist[wv][lane + 64 * i] = 0u;
    if (lane == 0) cnt[wv] = 0u;
    wave_fence();

    const float invw  = (float)NB / (HI_BR - LO_BR);
    const int   dummy = NB + lane;

    // Pass 1: branch-free histogram. One DS atomic per element, always.
    #pragma unroll 4
    for (int j = 0; j < 16; ++j) {
        float4 t = xv[j * 64 + lane];
        const float* e = (const float*)&t;
        #pragma unroll
        for (int q = 0; q < 4; ++q) {
            float f  = e[q];
            float fc = fminf(fmaxf(f, LO_BR), HI_BR);
            int   b  = (int)((fc - LO_BR) * invw);
            b = min(b, NB - 1);                 // fc==HI exactly -> 255
            b = (f < LO_BR) ? dummy : b;        // below bracket -> own bin
            atomicAdd(&hist[wv][b], 1u);
        }
    }
    wave_fence();

    // Suffix sums over the 256 real bins (lane owns bins 4l..4l+3).
    uint4 bq = *((const uint4*)&hist[wv][lane * 4]);
    const int b0 = (int)bq.x, b1 = (int)bq.y, b2 = (int)bq.z, b3 = (int)bq.w;
    const int sl = b0 + b1 + b2 + b3;
    int t = sl;
    #pragma unroll
    for (int d = 1; d < 64; d <<= 1) {
        int o = __shfl_down(t, d, 64);
        if (lane + d < 64) t += o;
    }
    const int Stot = __shfl(t, 0, 64);  // count(f >= LO) incl. >=HI tail
    const int E    = t - sl;            // count in bins > 4l+3

    const int c3 = b3, c2 = c3 + b2, c1 = c2 + b1, c0 = c1 + b0;
    int pickq = -1, gtv = 0, cinv = 0;
    if (Stot >= KSEL) {
        if      (E + c0 >= KSEL && E + c1 < KSEL) { pickq = 0; gtv = E + c1; cinv = b0; }
        else if (E + c1 >= KSEL && E + c2 < KSEL) { pickq = 1; gtv = E + c2; cinv = b1; }
        else if (E + c2 >= KSEL && E + c3 < KSEL) { pickq = 2; gtv = E + c3; cinv = b2; }
        else if (E + c3 >= KSEL && E      < KSEL) { pickq = 3; gtv = E;      cinv = b3; }
    }
    unsigned long long pm = __ballot(pickq >= 0);
    bool fallback = (Stot < KSEL) || (pm == 0ull);
    int bsel = 0, rr = 0, cin = 0;
    if (!fallback) {
        int src = __ffsll(pm) - 1;
        bsel = src * 4 + __shfl(pickq, src, 64);
        rr   = KSEL - __shfl(gtv, src, 64);   // rr-th largest inside bin
        cin  = __shfl(cinv, src, 64);
        if (cin > M_LIST) fallback = true;    // huge bin (e.g. 0 or 255)
    }

    if (!fallback) {
        // Pass 2: gather chosen bin's (value, index). Row is L1-hot (16 KB).
        #pragma unroll 4
        for (int j = 0; j < 16; ++j) {
            float4 tt = xv[j * 64 + lane];
            const float* e = (const float*)&tt;
            #pragma unroll
            for (int q = 0; q < 4; ++q) {
                float f  = e[q];
                float fc = fminf(fmaxf(f, LO_BR), HI_BR);
                int   b  = min((int)((fc - LO_BR) * invw), NB - 1);
                if (f >= LO_BR && b == bsel) {
                    unsigned p = atomicAdd(&cnt[wv], 1u);
                    lv[wv][p] = f;
                    li[wv][p] = (j * 64 + lane) * 4 + q;
                }
            }
        }
        wave_fence();
        const int c = (int)cnt[wv];           // == cin <= M_LIST

        // Parallel rank: value desc, index asc (top_k's stable order).
        float fv = 0.f; int fi = 0; int rank = -1;
        if (lane < c) {
            fv = lv[wv][lane]; fi = li[wv][lane];
            rank = 0;
            for (int m2 = 0; m2 < c; ++m2) {
                float gv = lv[wv][m2]; int gi = li[wv][m2];
                rank += ((gv > fv) || (gv == fv && gi < fi)) ? 1 : 0;
            }
        }
        unsigned long long mt = __ballot(rank == rr - 1);
        int lt = __ffsll(mt) - 1;
        const float T  = __shfl(fv, lt, 64);
        const int   Ti = __shfl(fi, lt, 64);
        int cut = INT_MAX;  // accept all equals unless a tied one is excluded
        unsigned long long mn = __ballot(rank == rr);
        if (mn != 0ull) {
            int ln = __ffsll(mn) - 1;
            float fn = __shfl(fv, ln, 64);
            if (fn == T) cut = Ti + 1;
        }
        if (lane == 0) tc[row] = make_int2(__float_as_int(T), cut);
        return;
    }

    // ---- exact fallback (cold): bit binary search, global re-reads ---------
    auto waveRedAll = [&](int c) -> int {
        #pragma unroll
        for (int d = 1; d < 64; d <<= 1) c += __shfl_xor(c, d, 64);
        return c;
    };
    auto cntGe = [&](uint32_t thr) -> int {
        int c = 0;
        for (int j = 0; j < 16; ++j) {
            float4 tt = xv[j * 64 + lane];
            const float* e = (const float*)&tt;
            #pragma unroll
            for (int q = 0; q < 4; ++q) c += (f2key(e[q]) >= thr) ? 1 : 0;
        }
        return waveRedAll(c);
    };

    uint32_t klo = 0u, khi = 0xFFFFFFFFu;
    while (klo < khi) {                   // max key with cntGe >= KSEL
        uint32_t d   = khi - klo;
        uint32_t mid = klo + (d >> 1) + (d & 1u);
        if (cntGe(mid) >= KSEL) klo = mid; else khi = mid - 1u;
    }
    const uint32_t Tkey = klo;
    const int c_ge = cntGe(Tkey);
    const int c_gt = (Tkey == 0xFFFFFFFFu) ? 0 : cntGe(Tkey + 1u);
    const int need_eq = KSEL - c_gt;
    const int cnt_eq  = c_ge - c_gt;

    int cut = INT_MAX;
    if (need_eq < cnt_eq) {
        int l2 = 0, h2 = N_FEAT;   // smallest m: count(==Tkey, g<m) >= need_eq
        while (l2 < h2) {
            int mid = (l2 + h2) >> 1;
            int c = 0;
            for (int j = 0; j < 16; ++j) {
                float4 tt = xv[j * 64 + lane];
                const float* e = (const float*)&tt;
                #pragma unroll
                for (int q = 0; q < 4; ++q) {
                    int g = (j * 64 + lane) * 4 + q;
                    c += (f2key(e[q]) == Tkey && g < mid) ? 1 : 0;
                }
            }
            if (waveRedAll(c) >= need_eq) h2 = mid; else l2 = mid + 1;
        }
        cut = l2;
    }
    if (lane == 0) tc[row] = make_int2(__float_as_int(key2f(Tkey)), cut);
}

// ---------------------------------------------------------------- kernel B --
__global__ __launch_bounds__(256, 8)
void apply_kernel(const float* __restrict__ x, const int2* __restrict__ tc,
                  float* __restrict__ out, int nrows) {
    const int blk = blockIdx.x;                    // 4 contiguous rows/block
    const size_t base4 = (size_t)blk * (4 * (N_FEAT / 4));
    const float4* __restrict__ xv = (const float4*)x + base4;
    float4* __restrict__ ov       = (float4*)out + base4;

    const int r0 = blk * 4;
    const int rm = nrows - 1;
    int2 t0 = tc[min(r0 + 0, rm)];
    int2 t1 = tc[min(r0 + 1, rm)];
    int2 t2 = tc[min(r0 + 2, rm)];
    int2 t3 = tc[min(r0 + 3, rm)];

    #pragma unroll
    for (int it = 0; it < 16; ++it) {
        const int i = it * 256 + (int)threadIdx.x;  // float4 idx within block
        const int rl = it >> 2;                     // compile-time constant
        if (r0 + rl >= nrows) continue;
        int2 tcr = (rl == 0) ? t0 : (rl == 1) ? t1 : (rl == 2) ? t2 : t3;
        const float T  = __int_as_float(tcr.x);
        const int  cut = tcr.y;

        float4 v = xv[i];
        const float* e = (const float*)&v;
        float4 o; float* oe = (float*)&o;
        const int gbase = (i & (N_FEAT / 4 - 1)) * 4;  // elem idx within row
        #pragma unroll
        for (int q = 0; q < 4; ++q) {
            float f = e[q];
            int   g = gbase + q;
            bool acc = (f > T) | ((f == T) & (g < cut));
            oe[q] = f * (acc ? GAINF : LEAKG);
        }
        ov[i] = o;
    }
}

extern "C" void kernel_launch(void* const* d_in, const int* in_sizes, int n_in,
                              void* d_out, int out_size, void* d_ws, size_t ws_size,
                              hipStream_t stream) {
    const float* x = (const float*)d_in[0];
    float* out = (float*)d_out;
    int2* tc = (int2*)d_ws;
    const int nrows = in_sizes[0] / N_FEAT;

    const int blocksA = (nrows + WPB - 1) / WPB;
    select_kernel<<<blocksA, THREADS, 0, stream>>>(x, tc, nrows);

    const int blocksB = (nrows + 3) / 4;
    apply_kernel<<<blocksB, 256, 0, stream>>>(x, tc, out, nrows);
}

// Round 4
// 263.519 us; speedup vs baseline: 1.0329x; 1.0329x over previous
//
#include <hip/hip_runtime.h>
#include <cstdint>
#include <climits>

// LeakyTopKActivation: out = x * mask * GAIN, mask = 1.0 on per-row top-k
// (k = 614 of 4096, stable ties by lowest index), LEAK=0.1 elsewhere.
//
// Single fused kernel, wave-per-row, ZERO barriers (all coordination is
// wave-synchronous: LDS fences + shfl/ballot). Row data is NOT register-
// resident (keeps VGPR low for occupancy); the gather and apply passes
// re-read the row from global (L2/L3-hot, just streamed by this wave).
//   pass 1: bracketed 256-bin histogram over [0.7,1.4) via LDS atomics
//           (~16% of elements in-bracket; >=HI counted in registers).
//   scan:   wave suffix-scan -> exact bin + rank within bin.
//   pass 2: gather the chosen bin's ~3 (value,index) pairs (L2-hot re-read),
//           parallel rank -> exact threshold T + tie cut index.
//   pass 3: apply. Fast path (no boundary tie, wave-uniform): 3 VALU/elem
//           out = f * (f>=T ? 3.0 : 0.3). Tie path keeps exact index logic.
// Exact bit-binary-search fallback (global re-reads) if the bracket misses —
// correctness never depends on the data distribution.

namespace {
constexpr int   N_FEAT  = 4096;
constexpr int   KSEL    = 614;      // max(int(4096*0.15),1)
constexpr int   NB      = 256;      // bins over [LO,HI)
constexpr int   WPB     = 4;        // waves (rows) per block
constexpr int   THREADS = 64 * WPB;
constexpr float LO_BR   = 0.70f;
constexpr float HI_BR   = 1.40f;
constexpr float GAINF   = 3.0f;
constexpr float LEAKG   = 0.3f;     // LEAK * GAIN
constexpr int   M_LIST  = 32;       // max gathered candidates in chosen bin
}

__device__ __forceinline__ void wave_fence() {
    // DS ops complete in-order within a wave; stops compiler reordering and
    // waits LDS atomics before dependent reads. No s_barrier anywhere.
    asm volatile("s_waitcnt lgkmcnt(0)" ::: "memory");
}

__device__ __forceinline__ uint32_t f2key(float f) {
    uint32_t u = __float_as_uint(f);
    return u ^ ((uint32_t)(((int32_t)u) >> 31) | 0x80000000u);
}

__global__ __launch_bounds__(THREADS, 6)
void ltk_fused(const float* __restrict__ x, float* __restrict__ out,
               int nrows) {
    const int lane = threadIdx.x & 63;
    const int wv   = threadIdx.x >> 6;
    const int row  = blockIdx.x * WPB + wv;   // wave-uniform
    if (row >= nrows) return;

    __shared__ unsigned int hist[WPB][NB];
    __shared__ float        lv[WPB][M_LIST];
    __shared__ int          li[WPB][M_LIST];
    __shared__ unsigned int cnt[WPB];

    const float4* __restrict__ xv = (const float4*)(x + (size_t)row * N_FEAT);
    float4* __restrict__ ov       = (float4*)(out + (size_t)row * N_FEAT);

    *((uint4*)&hist[wv][lane * 4]) = make_uint4(0u, 0u, 0u, 0u);
    if (lane == 0) cnt[wv] = 0u;
    wave_fence();

    const float invw = (float)NB / (HI_BR - LO_BR);

    // ---- pass 1: histogram (atomic only for ~16% in-bracket elements) ------
    int ca = 0;
    #pragma unroll 4
    for (int j = 0; j < 16; ++j) {
        float4 t = xv[j * 64 + lane];
        const float* e = (const float*)&t;
        #pragma unroll
        for (int q = 0; q < 4; ++q) {
            float f = e[q];
            ca += (f >= HI_BR) ? 1 : 0;
            if (f >= LO_BR && f < HI_BR) {
                int b = min((int)((f - LO_BR) * invw), NB - 1);
                atomicAdd(&hist[wv][b], 1u);
            }
        }
    }
    #pragma unroll
    for (int d = 1; d < 64; d <<= 1) ca += __shfl_xor(ca, d, 64);
    wave_fence();

    const int K2 = KSEL - ca;    // rank still needed within/below bracket

    // ---- suffix-scan the 256 bins (lane owns bins 4l..4l+3) ----------------
    uint4 bq = *((const uint4*)&hist[wv][lane * 4]);
    const int b0 = (int)bq.x, b1 = (int)bq.y, b2 = (int)bq.z, b3 = (int)bq.w;
    const int sl = b0 + b1 + b2 + b3;
    int t = sl;
    #pragma unroll
    for (int d = 1; d < 64; d <<= 1) {
        int o = __shfl_down(t, d, 64);
        if (lane + d < 64) t += o;
    }
    const int Stot = __shfl(t, 0, 64);  // total in bracket
    const int E    = t - sl;            // count in bins > 4l+3

    const int c3 = b3, c2 = c3 + b2, c1 = c2 + b1, c0 = c1 + b0;
    int pickq = -1, gtv = 0, cinv = 0;
    if (K2 > 0) {
        if      (E + c0 >= K2 && E + c1 < K2) { pickq = 0; gtv = E + c1; cinv = b0; }
        else if (E + c1 >= K2 && E + c2 < K2) { pickq = 1; gtv = E + c2; cinv = b1; }
        else if (E + c2 >= K2 && E + c3 < K2) { pickq = 2; gtv = E + c3; cinv = b2; }
        else if (E + c3 >= K2 && E      < K2) { pickq = 3; gtv = E;      cinv = b3; }
    }
    unsigned long long pm = __ballot(pickq >= 0);
    bool fallback = (K2 <= 0) || (Stot < K2) || (pm == 0ull);
    int bsel = 0, rr = 0, cin = 0;
    if (!fallback) {
        int src = __ffsll(pm) - 1;
        bsel = src * 4 + __shfl(pickq, src, 64);
        rr   = K2 - __shfl(gtv, src, 64);   // rr-th largest inside bin
        cin  = __shfl(cinv, src, 64);
        if (cin > M_LIST) fallback = true;
    }

    if (!fallback) {
        // ---- pass 2: gather chosen bin's (value,index); row is cache-hot ---
        #pragma unroll 4
        for (int j = 0; j < 16; ++j) {
            float4 tt = xv[j * 64 + lane];
            const float* e = (const float*)&tt;
            #pragma unroll
            for (int q = 0; q < 4; ++q) {
                float f = e[q];
                if (f >= LO_BR && f < HI_BR) {
                    int b = min((int)((f - LO_BR) * invw), NB - 1);
                    if (b == bsel) {
                        unsigned p = atomicAdd(&cnt[wv], 1u);
                        lv[wv][p] = f;
                        li[wv][p] = (j * 64 + lane) * 4 + q;
                    }
                }
            }
        }
        wave_fence();
        const int c = (int)cnt[wv];         // == cin <= M_LIST

        // Parallel rank: value desc, index asc (top_k's stable order).
        float fv = 0.f; int fi = 0; int rank = -1;
        if (lane < c) {
            fv = lv[wv][lane]; fi = li[wv][lane];
            rank = 0;
            for (int m2 = 0; m2 < c; ++m2) {
                float gv = lv[wv][m2]; int gi = li[wv][m2];
                rank += ((gv > fv) || (gv == fv && gi < fi)) ? 1 : 0;
            }
        }
        unsigned long long mt = __ballot(rank == rr - 1);
        int lt = __ffsll(mt) - 1;
        const float T  = __shfl(fv, lt, 64);
        const int   Ti = __shfl(fi, lt, 64);
        int cut = INT_MAX;  // accept all equals unless a tied one is excluded
        unsigned long long mn = __ballot(rank == rr);
        if (mn != 0ull) {
            int ln = __ffsll(mn) - 1;
            float fn = __shfl(fv, ln, 64);
            if (fn == T) cut = Ti + 1;
        }

        // ---- pass 3: apply (re-read, cache-hot) ----------------------------
        if (cut == INT_MAX) {
            // no boundary tie (the overwhelmingly common case): 3 VALU/elem
            #pragma unroll 4
            for (int j = 0; j < 16; ++j) {
                float4 vv = xv[j * 64 + lane];
                const float* e = (const float*)&vv;
                float4 o; float* oe = (float*)&o;
                #pragma unroll
                for (int q = 0; q < 4; ++q) {
                    float f = e[q];
                    oe[q] = f * ((f >= T) ? GAINF : LEAKG);
                }
                ov[j * 64 + lane] = o;
            }
        } else {
            #pragma unroll 4
            for (int j = 0; j < 16; ++j) {
                float4 vv = xv[j * 64 + lane];
                const float* e = (const float*)&vv;
                float4 o; float* oe = (float*)&o;
                #pragma unroll
                for (int q = 0; q < 4; ++q) {
                    float f = e[q];
                    int g = (j * 64 + lane) * 4 + q;
                    bool acc = (f > T) || (f == T && g < cut);
                    oe[q] = f * (acc ? GAINF : LEAKG);
                }
                ov[j * 64 + lane] = o;
            }
        }
        return;
    }

    // ---- exact fallback (cold): bit binary search, global re-reads ---------
    auto waveRedAll = [&](int c) -> int {
        #pragma unroll
        for (int d = 1; d < 64; d <<= 1) c += __shfl_xor(c, d, 64);
        return c;
    };
    auto cntGe = [&](uint32_t thr) -> int {
        int c = 0;
        for (int j = 0; j < 16; ++j) {
            float4 tt = xv[j * 64 + lane];
            const float* e = (const float*)&tt;
            #pragma unroll
            for (int q = 0; q < 4; ++q) c += (f2key(e[q]) >= thr) ? 1 : 0;
        }
        return waveRedAll(c);
    };

    uint32_t klo = 0u, khi = 0xFFFFFFFFu;
    while (klo < khi) {                   // max key with cntGe >= KSEL
        uint32_t d   = khi - klo;
        uint32_t mid = klo + (d >> 1) + (d & 1u);
        if (cntGe(mid) >= KSEL) klo = mid; else khi = mid - 1u;
    }
    const uint32_t Tkey = klo;
    const int c_ge = cntGe(Tkey);
    const int c_gt = (Tkey == 0xFFFFFFFFu) ? 0 : cntGe(Tkey + 1u);
    const int need_eq = KSEL - c_gt;
    const int cnt_eq  = c_ge - c_gt;

    int cut = INT_MAX;
    if (need_eq < cnt_eq) {
        int l2 = 0, h2 = N_FEAT;   // smallest m: count(==Tkey, g<m) >= need_eq
        while (l2 < h2) {
            int mid = (l2 + h2) >> 1;
            int c = 0;
            for (int j = 0; j < 16; ++j) {
                float4 tt = xv[j * 64 + lane];
                const float* e = (const float*)&tt;
                #pragma unroll
                for (int q = 0; q < 4; ++q) {
                    int g = (j * 64 + lane) * 4 + q;
                    c += (f2key(e[q]) == Tkey && g < mid) ? 1 : 0;
                }
            }
            if (waveRedAll(c) >= need_eq) h2 = mid; else l2 = mid + 1;
        }
        cut = l2;
    }

    for (int j = 0; j < 16; ++j) {
        float4 vv = xv[j * 64 + lane];
        const float* e = (const float*)&vv;
        float4 o; float* oe = (float*)&o;
        #pragma unroll
        for (int q = 0; q < 4; ++q) {
            float f = e[q];
            uint32_t kk = f2key(f);
            int g = (j * 64 + lane) * 4 + q;
            bool acc = (kk > Tkey) || (kk == Tkey && g < cut);
            oe[q] = f * (acc ? GAINF : LEAKG);
        }
        ov[j * 64 + lane] = o;
    }
}

extern "C" void kernel_launch(void* const* d_in, const int* in_sizes, int n_in,
                              void* d_out, int out_size, void* d_ws, size_t ws_size,
                              hipStream_t stream) {
    const float* x = (const float*)d_in[0];
    float* out = (float*)d_out;
    const int nrows = in_sizes[0] / N_FEAT;
    const int blocks = (nrows + WPB - 1) / WPB;
    ltk_fused<<<blocks, THREADS, 0, stream>>>(x, out, nrows);
}

// Round 5
// 226.351 us; speedup vs baseline: 1.2025x; 1.1642x over previous
//
#include <hip/hip_runtime.h>
#include <cstdint>
#include <climits>

// LeakyTopKActivation: out = x * mask * GAIN, mask = 1.0 on per-row top-k
// (k = 614 of 4096, stable ties by lowest index), LEAK=0.1 elsewhere.
//
// Block-per-row, 256 threads, 16 elems/thread REGISTER-RESIDENT (read x
// exactly once). Exact selection:
//   1) 256-bin histogram over [0.7, 1.4) via LDS atomics; f >= HI clamps
//      into bin 255 (no separate "above" count). f < LO skipped (~76%).
//   2) per-wave REDUNDANT suffix-scan of the 256 bins (shfl) -> exact bin
//      holding the k-th value + rank inside it. No cross-wave reduction.
//   3) gather that bin's ~3 (value,index) pairs to LDS (block atomics),
//      per-wave redundant parallel rank -> exact threshold T + tie cut.
//   4) apply from registers: out = f * (f>=T ? 3.0 : 0.3) (3 VALU/elem
//      fast path; exact index-tie path when a boundary tie exists).
// 3 barriers total. Exact block-wide bit-binary-search fallback (from
// registers) if the bracket misses or the bin is huge — correctness never
// depends on the data distribution.

namespace {
constexpr int   N_FEAT  = 4096;
constexpr int   KSEL    = 614;      // max(int(4096*0.15),1)
constexpr int   NB      = 256;      // bins over [LO,HI); bin 255 absorbs >=HI
constexpr int   THREADS = 256;
constexpr int   EPT     = 16;       // elements per thread (4 x float4)
constexpr float LO_BR   = 0.70f;
constexpr float HI_BR   = 1.40f;
constexpr float GAINF   = 3.0f;
constexpr float LEAKG   = 0.3f;     // LEAK * GAIN
constexpr int   M_LIST  = 32;       // max gathered candidates in chosen bin
}

__device__ __forceinline__ uint32_t f2key(float f) {
    uint32_t u = __float_as_uint(f);
    return u ^ ((uint32_t)(((int32_t)u) >> 31) | 0x80000000u);
}

__global__ __launch_bounds__(THREADS, 8)
void ltk_block(const float* __restrict__ x, float* __restrict__ out) {
    const int tid  = threadIdx.x;
    const int lane = tid & 63;

    __shared__ unsigned int hist[NB];
    __shared__ float        lv[M_LIST];
    __shared__ int          li[M_LIST];
    __shared__ unsigned int cnt;
    __shared__ unsigned int sh_red;

    const float4* __restrict__ xv = (const float4*)(x + (size_t)blockIdx.x * N_FEAT);
    float4* __restrict__ ov       = (float4*)(out + (size_t)blockIdx.x * N_FEAT);

    // Issue all 4 coalesced loads first; latency overlaps zero+barrier.
    float4 v[4];
    #pragma unroll
    for (int j = 0; j < 4; ++j) v[j] = xv[j * THREADS + tid];

    hist[tid] = 0u;
    if (tid == 0) cnt = 0u;
    __syncthreads();

    // ---- pass 1: histogram. Atomic only for f >= LO (~24% of elements);
    //      f >= HI clamps into bin 255.
    const float invw = (float)NB / (HI_BR - LO_BR);
    #pragma unroll
    for (int j = 0; j < 4; ++j) {
        const float* e = (const float*)&v[j];
        #pragma unroll
        for (int q = 0; q < 4; ++q) {
            float f = e[q];
            if (f >= LO_BR) {
                int b = min((int)((f - LO_BR) * invw), NB - 1);
                atomicAdd(&hist[b], 1u);
            }
        }
    }
    __syncthreads();

    // ---- per-wave redundant suffix-scan (lane owns bins 4l..4l+3) ----------
    uint4 bq = *((const uint4*)&hist[lane * 4]);
    const int b0 = (int)bq.x, b1 = (int)bq.y, b2 = (int)bq.z, b3 = (int)bq.w;
    const int sl = b0 + b1 + b2 + b3;
    int t = sl;
    #pragma unroll
    for (int d = 1; d < 64; d <<= 1) {
        int o = __shfl_down(t, d, 64);
        if (lane + d < 64) t += o;
    }
    const int Stot = __shfl(t, 0, 64);  // count(f >= LO)
    const int E    = t - sl;            // count in bins > 4l+3

    const int c3 = b3, c2 = c3 + b2, c1 = c2 + b1, c0 = c1 + b0;
    int pickq = -1, gtv = 0, cinv = 0;
    if (Stot >= KSEL) {
        if      (E + c0 >= KSEL && E + c1 < KSEL) { pickq = 0; gtv = E + c1; cinv = b0; }
        else if (E + c1 >= KSEL && E + c2 < KSEL) { pickq = 1; gtv = E + c2; cinv = b1; }
        else if (E + c2 >= KSEL && E + c3 < KSEL) { pickq = 2; gtv = E + c3; cinv = b2; }
        else if (E + c3 >= KSEL && E      < KSEL) { pickq = 3; gtv = E;      cinv = b3; }
    }
    unsigned long long pm = __ballot(pickq >= 0);
    bool fallback = (Stot < KSEL) || (pm == 0ull);
    int bsel = 0, rr = 0, cin = 0;
    if (!fallback) {
        int src = __ffsll(pm) - 1;
        bsel = src * 4 + __shfl(pickq, src, 64);
        rr   = KSEL - __shfl(gtv, src, 64);   // rr-th largest inside bin
        cin  = __shfl(cinv, src, 64);
        if (cin > M_LIST) fallback = true;    // huge bin (incl. bsel==255 fold)
    }
    // fallback is block-uniform: every wave computed it from identical LDS.

    if (!fallback) {
        // ---- pass 2: gather chosen bin's (value, index) from registers -----
        #pragma unroll
        for (int j = 0; j < 4; ++j) {
            const float* e = (const float*)&v[j];
            #pragma unroll
            for (int q = 0; q < 4; ++q) {
                float f = e[q];
                if (f >= LO_BR) {
                    int b = min((int)((f - LO_BR) * invw), NB - 1);
                    if (b == bsel) {
                        unsigned p = atomicAdd(&cnt, 1u);
                        lv[p] = f;
                        li[p] = (j * THREADS + tid) * 4 + q;
                    }
                }
            }
        }
        __syncthreads();
        const int c = (int)cnt;               // == cin <= M_LIST

        // ---- per-wave redundant parallel rank (value desc, index asc) ------
        float fv = 0.f; int fi = 0; int rank = -1;
        if (lane < c) {
            fv = lv[lane]; fi = li[lane];
            rank = 0;
            for (int m2 = 0; m2 < c; ++m2) {
                float gv = lv[m2]; int gi = li[m2];
                rank += ((gv > fv) || (gv == fv && gi < fi)) ? 1 : 0;
            }
        }
        unsigned long long mt = __ballot(rank == rr - 1);
        int lt = __ffsll(mt) - 1;
        const float T  = __shfl(fv, lt, 64);
        const int   Ti = __shfl(fi, lt, 64);
        int cut = INT_MAX;  // accept all equals unless a tied one is excluded
        unsigned long long mn = __ballot(rank == rr);
        if (mn != 0ull) {
            int ln = __ffsll(mn) - 1;
            float fn = __shfl(fv, ln, 64);
            if (fn == T) cut = Ti + 1;
        }

        // ---- pass 3: apply from registers ----------------------------------
        if (cut == INT_MAX) {
            #pragma unroll
            for (int j = 0; j < 4; ++j) {
                const float* e = (const float*)&v[j];
                float4 o; float* oe = (float*)&o;
                #pragma unroll
                for (int q = 0; q < 4; ++q) {
                    float f = e[q];
                    oe[q] = f * ((f >= T) ? GAINF : LEAKG);
                }
                ov[j * THREADS + tid] = o;
            }
        } else {
            #pragma unroll
            for (int j = 0; j < 4; ++j) {
                const float* e = (const float*)&v[j];
                float4 o; float* oe = (float*)&o;
                #pragma unroll
                for (int q = 0; q < 4; ++q) {
                    float f = e[q];
                    int g = (j * THREADS + tid) * 4 + q;
                    bool acc = (f > T) || (f == T && g < cut);
                    oe[q] = f * (acc ? GAINF : LEAKG);
                }
                ov[j * THREADS + tid] = o;
            }
        }
        return;
    }

    // ---- exact fallback: block-wide bit binary search (never hot) ----------
    uint32_t keys[EPT];
    #pragma unroll
    for (int j = 0; j < 4; ++j) {
        const float* e = (const float*)&v[j];
        #pragma unroll
        for (int q = 0; q < 4; ++q) keys[j * 4 + q] = f2key(e[q]);
    }

    auto blockReduce = [&](unsigned int c) -> int {
        #pragma unroll
        for (int d = 1; d < 64; d <<= 1) c += __shfl_xor(c, d, 64);
        if (tid == 0) sh_red = 0u;
        __syncthreads();
        if (lane == 0) atomicAdd(&sh_red, c);
        __syncthreads();
        unsigned int r2 = sh_red;
        __syncthreads();
        return (int)r2;
    };
    auto cntGe = [&](uint32_t thr) -> int {
        unsigned int c = 0;
        #pragma unroll
        for (int i = 0; i < EPT; ++i) c += (keys[i] >= thr) ? 1u : 0u;
        return blockReduce(c);
    };

    uint32_t klo = 0u, khi = 0xFFFFFFFFu;
    while (klo < khi) {                   // max key with cntGe >= KSEL
        uint32_t d   = khi - klo;
        uint32_t mid = klo + (d >> 1) + (d & 1u);
        if (cntGe(mid) >= KSEL) klo = mid; else khi = mid - 1u;
    }
    const uint32_t Tkey = klo;
    const int c_ge = cntGe(Tkey);
    const int c_gt = (Tkey == 0xFFFFFFFFu) ? 0 : cntGe(Tkey + 1u);
    const int need_eq = KSEL - c_gt;
    const int cnt_eq  = c_ge - c_gt;

    int cut = INT_MAX;
    if (need_eq < cnt_eq) {
        int l2 = 0, h2 = N_FEAT;   // smallest m: count(==Tkey, g<m) >= need_eq
        while (l2 < h2) {
            int mid = (l2 + h2) >> 1;
            unsigned int c = 0;
            #pragma unroll
            for (int i = 0; i < EPT; ++i) {
                int g = ((i >> 2) * THREADS + tid) * 4 + (i & 3);
                c += (keys[i] == Tkey && g < mid) ? 1u : 0u;
            }
            if (blockReduce(c) >= need_eq) h2 = mid; else l2 = mid + 1;
        }
        cut = l2;
    }

    #pragma unroll
    for (int j = 0; j < 4; ++j) {
        const float* e = (const float*)&v[j];
        float4 o; float* oe = (float*)&o;
        #pragma unroll
        for (int q = 0; q < 4; ++q) {
            float f = e[q];
            uint32_t kk = keys[j * 4 + q];
            int g = (j * THREADS + tid) * 4 + q;
            bool acc = (kk > Tkey) || (kk == Tkey && g < cut);
            oe[q] = f * (acc ? GAINF : LEAKG);
        }
        ov[j * THREADS + tid] = o;
    }
}

extern "C" void kernel_launch(void* const* d_in, const int* in_sizes, int n_in,
                              void* d_out, int out_size, void* d_ws, size_t ws_size,
                              hipStream_t stream) {
    const float* x = (const float*)d_in[0];
    float* out = (float*)d_out;
    const int nrows = in_sizes[0] / N_FEAT;
    ltk_block<<<nrows, THREADS, 0, stream>>>(x, out);
}